// Round 15
// baseline (31191.089 us; speedup 1.0000x reference)
//
#include <hip/hip_runtime.h>
#include <hip/hip_bf16.h>

// mLSTM persistent v15: parity-fused wide exchange.
// Producers embed step-parity in each bf16 LSB and issue 16B transposed
// stores (no drain, no flags). Consumers do validated 16B burst reads —
// the read IS the sync (v11 protocol + v13/v14 request economy).
// L=512, N=32, H=1024, 2 layers. Out: ys | hs(2,32,1024) | cs(2,32,1024), fp32.

typedef unsigned short u16;
typedef unsigned int u32;
typedef unsigned long long u64;
typedef __attribute__((ext_vector_type(8))) short bf16x8;
typedef __attribute__((ext_vector_type(4))) float f32x4;
typedef __attribute__((ext_vector_type(4))) unsigned int u32x4;

#define LSEQ 512
#define NB   32
#define HD   1024
#define G4   4096
#define YSZ  (LSEQ*NB*HD)
#define NH32 (NB*HD)
#define SEG  64
#define NSEG (LSEQ/SEG)
#define PERSIST_LDS 163840   // 128KB Wgm + 32KB Wmh

#define ATOMIC_RLX __ATOMIC_RELAXED
#define SCOPE_AGT __HIP_MEMORY_SCOPE_AGENT

__device__ __forceinline__ float b2f(u16 u) {
    u32 i = ((u32)u) << 16; float f; __builtin_memcpy(&f, &i, 4); return f;
}
__device__ __forceinline__ u16 f2b(float f) {
    u32 x; __builtin_memcpy(&x, &f, 4);
    return (u16)((x + 0x7fffu + ((x >> 16) & 1u)) >> 16);
}
__device__ __forceinline__ int SW(int row, int byte) { return byte ^ ((row & 7) << 4); }

// Validated burst read: 32x 16B coherence-point loads; every u16 must carry
// the expected parity LSB (expw = 0x00010001 or 0). Retry until fresh.
// Per-element parity catches stale AND torn sectors. The read IS the sync.
__device__ __forceinline__ void load_rowv(const char* base, u32x4* dst, u32 expw) {
    for (;;) {
#pragma unroll
        for (int kt = 0; kt < 32; ++kt) {
            u64 a = (u64)(base + kt * 64);
            asm volatile("global_load_dwordx4 %0, %1, off sc0 sc1"
                         : "=v"(dst[kt]) : "v"(a));
        }
        asm volatile("s_waitcnt vmcnt(0)" ::: "memory");
        u32 bad = 0;
#pragma unroll
        for (int kt = 0; kt < 32; ++kt)
#pragma unroll
            for (int p = 0; p < 4; ++p)
                bad |= (dst[kt][p] ^ expw) & 0x00010001u;
        if (__all(bad == 0)) break;
        __builtin_amdgcn_s_sleep(2);
    }
    __builtin_amdgcn_sched_barrier(0);
}

// Producer: transpose per-lane row-values (value(R,C): R=rowbase+lk*4+r,
// C=colbase+l16, held as mu[r] in lane lk*16+l16) so lanes 0..31 each emit
// ONE contiguous 16B store (row Rl=d>>1, 8 cols at 8*(d&1)). Parity already
// embedded in mu by the caller. [verified correct in v14]
__device__ __forceinline__ void store_t16(u16* ebuf, int rowbase, int colbase,
                                          const u16 mu[4]) {
    const int d = threadIdx.x & 63;
    u32 wlo = (u32)mu[0] | ((u32)mu[1] << 16);
    u32 whi = (u32)mu[2] | ((u32)mu[3] << 16);
    const int Rl = d >> 1, half = d & 1;
    const int lks = Rl >> 2, r = Rl & 3;
    u32x4 outv;
#pragma unroll
    for (int p = 0; p < 4; ++p) {
        u32 v0, v1;
        {
            int s = lks * 16 + half * 8 + 2 * p;
            u32 a = (u32)__shfl((int)wlo, s);
            u32 bb = (u32)__shfl((int)whi, s);
            u32 pick = (r & 2) ? bb : a;
            v0 = (r & 1) ? (pick >> 16) : (pick & 0xFFFFu);
        }
        {
            int s = lks * 16 + half * 8 + 2 * p + 1;
            u32 a = (u32)__shfl((int)wlo, s);
            u32 bb = (u32)__shfl((int)whi, s);
            u32 pick = (r & 2) ? bb : a;
            v1 = (r & 1) ? (pick >> 16) : (pick & 0xFFFFu);
        }
        outv[p] = v0 | (v1 << 16);
    }
    if (d < 32) {
        u64 addr = (u64)ebuf + (size_t)(rowbase + Rl) * 2048 + colbase * 2 + half * 16;
        asm volatile("global_store_dwordx4 %0, %1, off sc0 sc1"
                     :: "v"(addr), "v"(outv) : "memory");
    }
}

// ---------------- init / conversion ----------------
__global__ void k_fill(u32* __restrict__ d, int n, u32 v) {
    int i = blockIdx.x * blockDim.x + threadIdx.x;
    if (i < n) d[i] = v;
}
__global__ void k_cvt(const float* __restrict__ s, u16* __restrict__ d, long n) {
    long i = (long)blockIdx.x * blockDim.x + threadIdx.x;
    long stride = (long)gridDim.x * blockDim.x;
    for (; i < n; i += stride) d[i] = f2b(s[i]);
}

template<typename XT> __device__ __forceinline__ bf16x8 ld8(const XT* p);
template<> __device__ __forceinline__ bf16x8 ld8<u16>(const u16* p) {
    return *(const bf16x8*)p;
}
template<> __device__ __forceinline__ bf16x8 ld8<float>(const float* p) {
    float4 a = *(const float4*)p, b = *(const float4*)(p + 4);
    bf16x8 r;
    r[0]=(short)f2b(a.x); r[1]=(short)f2b(a.y); r[2]=(short)f2b(a.z); r[3]=(short)f2b(a.w);
    r[4]=(short)f2b(b.x); r[5]=(short)f2b(b.y); r[6]=(short)f2b(b.z); r[7]=(short)f2b(b.w);
    return r;
}

// ------- big GEMM: Out[M][ldo] = bf16(X[M][1024] @ W[ncols][1024]^T + bias) -------
template<typename XT>
__global__ __launch_bounds__(256) void k_gemm(
    const XT* __restrict__ X, const u16* __restrict__ W,
    const float* __restrict__ bias, u16* __restrict__ Out, int ldo)
{
    __shared__ u16 As[128][40];
    __shared__ u16 Bs[128][40];
    int bm = blockIdx.y, bn = blockIdx.x;
    int tid = threadIdx.x;
    int w = tid >> 6, lane = tid & 63;
    int wm = w >> 1, wn = w & 1;
    int l16 = lane & 15, lk = lane >> 4;

    f32x4 acc[4][4];
    #pragma unroll
    for (int i = 0; i < 4; ++i)
        #pragma unroll
        for (int j = 0; j < 4; ++j) acc[i][j] = (f32x4){0.f, 0.f, 0.f, 0.f};

    for (int kt = 0; kt < 32; ++kt) {
        __syncthreads();
        #pragma unroll
        for (int c = 0; c < 2; ++c) {
            int cid = tid + c * 256;
            int rrow = cid >> 2, kc = (cid & 3) * 8;
            *(bf16x8*)(&As[rrow][kc]) = ld8<XT>(X + (long)(bm * 128 + rrow) * HD + kt * 32 + kc);
            *(bf16x8*)(&Bs[rrow][kc]) = ld8<u16>(W + (long)(bn * 128 + rrow) * HD + kt * 32 + kc);
        }
        __syncthreads();
        bf16x8 af[4], bfr[4];
        #pragma unroll
        for (int mt = 0; mt < 4; ++mt)
            af[mt] = *(const bf16x8*)(&As[wm * 64 + mt * 16 + l16][lk * 8]);
        #pragma unroll
        for (int nt = 0; nt < 4; ++nt)
            bfr[nt] = *(const bf16x8*)(&Bs[wn * 64 + nt * 16 + l16][lk * 8]);
        #pragma unroll
        for (int mt = 0; mt < 4; ++mt)
            #pragma unroll
            for (int nt = 0; nt < 4; ++nt)
                acc[mt][nt] = __builtin_amdgcn_mfma_f32_16x16x32_bf16(
                    af[mt], bfr[nt], acc[mt][nt], 0, 0, 0);
    }
    #pragma unroll
    for (int mt = 0; mt < 4; ++mt)
        #pragma unroll
        for (int nt = 0; nt < 4; ++nt) {
            int colg = bn * 128 + wn * 64 + nt * 16 + l16;
            float bv = bias[colg];
            #pragma unroll
            for (int r = 0; r < 4; ++r) {
                int rowg = bm * 128 + wm * 64 + mt * 16 + lk * 4 + r;
                Out[(long)rowg * ldo + colg] = f2b(acc[mt][nt][r] + bv);
            }
        }
}

// ---------------- persistent recurrent kernel (one 64-step segment) ----------------
// 64 blocks x 256 thr, 1 block/CU (160KB LDS). Block b owns h/m-cols [16b,16b+16).
// Waves 2,3: phase1 (m), rt=w&1. Waves 0,1: phase2 (g/h/c), rt=w&1.
// No flags, no drains, no in-loop barriers: parity-validated reads are the sync.
__global__ __launch_bounds__(256, 1) void k_persist(
    const u16* __restrict__ Wmhb, const float* __restrict__ bmh,
    const u16* __restrict__ Wgmb,
    const u16* __restrict__ Ab,    // [512][32][1024] layer-local (tbi+t indexed)
    const u16* __restrict__ Gxb,   // [SEG][32][4096] segment-local
    u16* eh, u16* em,              // [32][1024] parity-tagged exchange
    float* __restrict__ cbuf,      // [32][1024] f32 c-state
    u16* __restrict__ yb, float* __restrict__ yf,
    float* __restrict__ tail,      // out + YSZ
    int l, int tbc, int tbi)
{
    extern __shared__ __align__(16) char lds[];
    const int tid = threadIdx.x;
    const int b = blockIdx.x;
    const int w = tid >> 6, lane = tid & 63;
    const int l16 = lane & 15, lk = lane >> 4;

    // ---- stage Wgm slice (4 gates x 16 cols = 128KB) + Wmh slice (16 cols = 32KB) ----
    for (int it = 0; it < 32; ++it) {
        int cch = tid + it * 256;
        int lr = cch >> 7, k8 = cch & 127;
        int g = lr >> 4, c16 = lr & 15;
        bf16x8 v = *(const bf16x8*)(Wgmb + (long)(g * 1024 + 16 * b + c16) * HD + k8 * 8);
        *(bf16x8*)(lds + SW(lr, lr * 2048 + k8 * 16)) = v;
    }
    for (int it = 0; it < 8; ++it) {
        int cch = tid + it * 256;
        int lr = cch >> 7, k8 = cch & 127;
        bf16x8 v = *(const bf16x8*)(Wmhb + (long)(16 * b + lr) * HD + k8 * 8);
        *(bf16x8*)(lds + 131072 + SW(lr, lr * 2048 + k8 * 16)) = v;
    }
    __syncthreads();   // only block-wide sync: LDS staging done

    const int colg = 16 * b + l16;
    const int rt = w & 1;
    const bool isP1 = (w >= 2);

    const float bcol = bmh[colg];
    const char* hbase = (const char*)eh + (size_t)(rt * 16 + l16) * 2048 + lk * 16;
    const char* mbase = (const char*)em + (size_t)(rt * 16 + l16) * 2048 + lk * 16;
    f32x4 creg = (f32x4){0.f, 0.f, 0.f, 0.f};
    if (!isP1)
        #pragma unroll
        for (int r = 0; r < 4; ++r)
            creg[r] = cbuf[(rt * 16 + lk * 4 + r) * HD + colg];

    if (isP1) {
        // ================= phase 1: m = A_t * (h @ Wmh^T + bmh) =================
        for (int t = 0; t < SEG; ++t) {
            const u32 gt = (u32)(tbc + t);
            const u32 expw_h = ((gt + 1) & 1u) ? 0x00010001u : 0u;  // h_{gt-1} parity
            const u16 pm = (u16)(gt & 1u);                          // m_gt parity
            const u16* At = Ab + (long)(tbi + t) * NH32;
            u16 atv[4];
            #pragma unroll
            for (int r = 0; r < 4; ++r)
                atv[r] = At[(rt * 16 + lk * 4 + r) * HD + colg];
            u32x4 hv[32];
            load_rowv(hbase, hv, expw_h);          // sync + data, fused
            f32x4 acc = (f32x4){0.f, 0.f, 0.f, 0.f};
            #pragma unroll
            for (int kt = 0; kt < 32; ++kt) {
                union { u32x4 q; bf16x8 v; } u;
                u.q = hv[kt];
                bf16x8 bfrag = *(const bf16x8*)(lds + 131072 +
                                SW(l16, l16 * 2048 + kt * 64 + lk * 16));
                acc = __builtin_amdgcn_mfma_f32_16x16x32_bf16(u.v, bfrag, acc, 0, 0, 0);
            }
            u16 mu[4];
            #pragma unroll
            for (int r = 0; r < 4; ++r)
                mu[r] = (u16)((f2b(b2f(atv[r]) * (acc[r] + bcol)) & 0xFFFEu) | pm);
            store_t16(em, rt * 16, 16 * b, mu);
            // no drain, no flag — parity carries validity
        }
    } else {
        // ===== phase 2: g = Gx_t + m @ Wgm^T; gates; h,c (all 4 gates per lane) =====
        for (int t = 0; t < SEG; ++t) {
            const u32 gt = (u32)(tbc + t);
            const u32 expw_m = (gt & 1u) ? 0x00010001u : 0u;        // m_gt parity
            const u16 pm = (u16)(gt & 1u);                          // h_gt parity
            const u16* Gx = Gxb + (long)t * NB * G4;
            u16 gxv[4][4];
            #pragma unroll
            for (int g = 0; g < 4; ++g)
                #pragma unroll
                for (int r = 0; r < 4; ++r)
                    gxv[g][r] = Gx[(long)(rt * 16 + lk * 4 + r) * G4 + g * 1024 + colg];
            u32x4 mv[32];
            load_rowv(mbase, mv, expw_m);          // sync + data, fused
            f32x4 gacc[4];
            #pragma unroll
            for (int g = 0; g < 4; ++g) gacc[g] = (f32x4){0.f, 0.f, 0.f, 0.f};
            #pragma unroll
            for (int kt = 0; kt < 32; ++kt) {
                union { u32x4 q; bf16x8 v; } u;
                u.q = mv[kt];
                #pragma unroll
                for (int g = 0; g < 4; ++g) {
                    int lr = g * 16 + l16;
                    bf16x8 bfrag = *(const bf16x8*)(lds + SW(lr, lr * 2048 + kt * 64 + lk * 16));
                    gacc[g] = __builtin_amdgcn_mfma_f32_16x16x32_bf16(u.v, bfrag, gacc[g], 0, 0, 0);
                }
            }
            float hn[4];
            u16 hu[4];
            #pragma unroll
            for (int r = 0; r < 4; ++r) {
                float ig = gacc[0][r] + b2f(gxv[0][r]);
                float fg = gacc[1][r] + b2f(gxv[1][r]);
                float zg = gacc[2][r] + b2f(gxv[2][r]);
                float og = gacc[3][r] + b2f(gxv[3][r]);
                float si = 1.f / (1.f + expf(-ig));
                float sf = 1.f / (1.f + expf(-fg));
                float so = 1.f / (1.f + expf(-og));
                float cn = sf * creg[r] + si * tanhf(zg);
                hn[r] = so * tanhf(cn);
                creg[r] = cn;
                hu[r] = (u16)((f2b(hn[r]) & 0xFFFEu) | pm);
            }
            store_t16(eh, rt * 16, 16 * b, hu);
            // ---- outputs (off the dependency chain) ----
            #pragma unroll
            for (int r = 0; r < 4; ++r) {
                int row = rt * 16 + lk * 4 + r;
                long yidx = (long)(tbi + t) * NH32 + (long)row * HD + colg;
                if (yb) yb[yidx] = f2b(hn[r]); else yf[yidx] = hn[r];
                if (tbi + t == LSEQ - 1) {
                    tail[(long)l * NH32 + row * HD + colg] = hn[r];
                    tail[2L * NH32 + (long)l * NH32 + row * HD + colg] = creg[r];
                }
            }
        }
        #pragma unroll
        for (int r = 0; r < 4; ++r)
            cbuf[(rt * 16 + lk * 4 + r) * HD + colg] = creg[r];
    }
}

extern "C" void kernel_launch(void* const* d_in, const int* in_sizes, int n_in,
                              void* d_out, int out_size, void* d_ws, size_t ws_size,
                              hipStream_t stream) {
    (void)in_sizes; (void)n_in; (void)out_size; (void)ws_size;
    const float* inputs = (const float*)d_in[0];
    const float* Wmx[2] = {(const float*)d_in[1], (const float*)d_in[8]};
    const float* Wmh[2] = {(const float*)d_in[2], (const float*)d_in[9]};
    const float* bmx[2] = {(const float*)d_in[3], (const float*)d_in[10]};
    const float* bmh[2] = {(const float*)d_in[4], (const float*)d_in[11]};
    const float* Wgx[2] = {(const float*)d_in[5], (const float*)d_in[12]};
    const float* Wgm[2] = {(const float*)d_in[6], (const float*)d_in[13]};
    const float* bg[2]  = {(const float*)d_in[7], (const float*)d_in[14]};
    float* out = (float*)d_out;

    char* ws = (char*)d_ws;
    const long MB = 1024L * 1024L;
    u16* Wmxb[2] = {(u16*)(ws + 0 * MB),  (u16*)(ws + 2 * MB)};
    u16* Wmhb[2] = {(u16*)(ws + 4 * MB),  (u16*)(ws + 6 * MB)};
    u16* Wgxb[2] = {(u16*)(ws + 8 * MB),  (u16*)(ws + 16 * MB)};
    u16* Wgmb[2] = {(u16*)(ws + 24 * MB), (u16*)(ws + 32 * MB)};
    u16* Yb  = (u16*)(ws + 40 * MB);   // 32MB bf16 layer-0 outputs
    u16* Ab  = (u16*)(ws + 72 * MB);   // 32MB bf16 A = x@Wmx+bmx (per layer)
    u16* Gxb = (u16*)(ws + 104 * MB);  // 16MB bf16 Gx chunk
    char* ex = ws + 120 * MB;
    u16* exch_h = (u16*)ex;                       // 64KB parity-tagged h
    u16* exch_m = (u16*)(ex + 65536);             // 64KB parity-tagged m
    float* cbuf = (float*)(ex + 131072);          // 128KB c-state

    hipFuncSetAttribute((const void*)k_persist,
                        hipFuncAttributeMaxDynamicSharedMemorySize, PERSIST_LDS);

    // init: h/m filled with parity-1 denormal words. h_{-1}=~0 valid at gt=0
    // (expects parity 1); m parity-1 = invalid for gt=0 (expects 0). c zeroed.
    k_fill<<<128, 256, 0, stream>>>((u32*)ex, 32768, 0x00010001u);
    hipMemsetAsync(cbuf, 0, 131072, stream);

    k_cvt<<<512, 256, 0, stream>>>(Wmx[0], Wmxb[0], (long)HD * HD);
    k_cvt<<<512, 256, 0, stream>>>(Wmx[1], Wmxb[1], (long)HD * HD);
    k_cvt<<<512, 256, 0, stream>>>(Wmh[0], Wmhb[0], (long)HD * HD);
    k_cvt<<<512, 256, 0, stream>>>(Wmh[1], Wmhb[1], (long)HD * HD);
    k_cvt<<<1024, 256, 0, stream>>>(Wgx[0], Wgxb[0], (long)G4 * HD);
    k_cvt<<<1024, 256, 0, stream>>>(Wgx[1], Wgxb[1], (long)G4 * HD);
    k_cvt<<<1024, 256, 0, stream>>>(Wgm[0], Wgmb[0], (long)G4 * HD);
    k_cvt<<<1024, 256, 0, stream>>>(Wgm[1], Wgmb[1], (long)G4 * HD);

    for (int l = 0; l < 2; ++l) {
        if (l == 0)
            k_gemm<float><<<dim3(8, 128), 256, 0, stream>>>(inputs, Wmxb[0], bmx[0], Ab, HD);
        else
            k_gemm<u16><<<dim3(8, 128), 256, 0, stream>>>(Yb, Wmxb[1], bmx[1], Ab, HD);
        for (int s = 0; s < NSEG; ++s) {
            if (l == 0)
                k_gemm<float><<<dim3(32, 16), 256, 0, stream>>>(
                    inputs + (long)s * SEG * NB * HD, Wgxb[0], bg[0], Gxb, G4);
            else
                k_gemm<u16><<<dim3(32, 16), 256, 0, stream>>>(
                    Yb + (long)s * SEG * NB * HD, Wgxb[1], bg[1], Gxb, G4);
            k_persist<<<64, 256, PERSIST_LDS, stream>>>(
                Wmhb[l], bmh[l], Wgmb[l], Ab, Gxb,
                exch_h, exch_m, cbuf,
                l ? nullptr : Yb, l ? out : nullptr, out + YSZ,
                l, l * LSEQ + s * SEG, s * SEG);
        }
    }
}

// Round 16
// 14133.435 us; speedup vs baseline: 2.2069x; 2.2069x over previous
//
#include <hip/hip_runtime.h>
#include <hip/hip_bf16.h>

// mLSTM persistent v16: v13 (best, 835us/seg) + fused next-segment prefetch
// GEMMs as extra blocks in the persist launch (fills the 192 idle CUs).
// L=512, N=32, H=1024, 2 layers. Out: ys | hs(2,32,1024) | cs(2,32,1024), fp32.

typedef unsigned short u16;
typedef unsigned int u32;
typedef unsigned long long u64;
typedef __attribute__((ext_vector_type(8))) short bf16x8;
typedef __attribute__((ext_vector_type(4))) float f32x4;
typedef __attribute__((ext_vector_type(4))) unsigned int u32x4;

#define LSEQ 512
#define NB   32
#define HD   1024
#define G4   4096
#define YSZ  (LSEQ*NB*HD)
#define NH32 (NB*HD)
#define SEG  64
#define NSEG (LSEQ/SEG)
#define PERSIST_LDS 163840   // 128KB Wgm + 32KB Wmh
#define GXBLK 512            // 32x16 tiles for Gx prefetch
#define ABLK  128            // 8x16 tiles for A prefetch

#define ATOMIC_RLX __ATOMIC_RELAXED
#define SCOPE_AGT __HIP_MEMORY_SCOPE_AGENT

__device__ __forceinline__ float b2f(u16 u) {
    u32 i = ((u32)u) << 16; float f; __builtin_memcpy(&f, &i, 4); return f;
}
__device__ __forceinline__ u16 f2b(float f) {
    u32 x; __builtin_memcpy(&x, &f, 4);
    return (u16)((x + 0x7fffu + ((x >> 16) & 1u)) >> 16);
}
__device__ __forceinline__ int SW(int row, int byte) { return byte ^ ((row & 7) << 4); }

// v13-proven poll: lane b gathers block b's 8B slot-pair; paced with s_sleep.
__device__ __forceinline__ void pollwait(const u32* flags, u32 target) {
    const int lane = threadIdx.x & 63;
    const u64* p = (const u64*)flags + (size_t)lane * 16;
    for (;;) {
        u64 v = __hip_atomic_load(p, ATOMIC_RLX, SCOPE_AGT);
        u32 lo = (u32)v, hi = (u32)(v >> 32);
        if (__all(lo >= target && hi >= target)) break;
        __builtin_amdgcn_s_sleep(4);
    }
    asm volatile("" ::: "memory");
}

// Consumer: 32x 16B coherence-point loads (sector-coalescing).
__device__ __forceinline__ void load_row16(const char* base, u32x4* dst) {
#pragma unroll
    for (int kt = 0; kt < 32; ++kt) {
        u64 a = (u64)(base + kt * 64);
        asm volatile("global_load_dwordx4 %0, %1, off sc0 sc1"
                     : "=v"(dst[kt]) : "v"(a));
    }
    asm volatile("s_waitcnt vmcnt(0)" ::: "memory");
    __builtin_amdgcn_sched_barrier(0);
}

// Producer: shuffle-transpose; each of lanes 0..63 emits one contiguous u64
// atomic store (row rl, 4 cols). [v13-proven]
__device__ __forceinline__ void store_transposed(u16* ebuf, int rowbase, int colbase,
                                                 const u16 mu[4]) {
    const int lane = threadIdx.x & 63;
    u32 wlo = (u32)mu[0] | ((u32)mu[1] << 16);
    u32 whi = (u32)mu[2] | ((u32)mu[3] << 16);
    const int rl = lane >> 2;
    const int r = rl & 3, lks = rl >> 2;
    u64 outv = 0;
#pragma unroll
    for (int i = 0; i < 4; ++i) {
        int s = lks * 16 + (lane & 3) * 4 + i;
        u32 a  = (u32)__shfl((int)wlo, s);
        u32 bb = (u32)__shfl((int)whi, s);
        u32 pick = (r & 2) ? bb : a;
        u32 val = (r & 1) ? (pick >> 16) : (pick & 0xFFFFu);
        outv |= (u64)val << (16 * i);
    }
    u64* dst = (u64*)(ebuf + (size_t)(rowbase + rl) * HD + colbase + (lane & 3) * 4);
    __hip_atomic_store(dst, outv, ATOMIC_RLX, SCOPE_AGT);
}

// ---------------- f32 -> bf16 conversion ----------------
__global__ void k_cvt(const float* __restrict__ s, u16* __restrict__ d, long n) {
    long i = (long)blockIdx.x * blockDim.x + threadIdx.x;
    long stride = (long)gridDim.x * blockDim.x;
    for (; i < n; i += stride) d[i] = f2b(s[i]);
}

template<typename XT> __device__ __forceinline__ bf16x8 ld8(const XT* p);
template<> __device__ __forceinline__ bf16x8 ld8<u16>(const u16* p) {
    return *(const bf16x8*)p;
}
template<> __device__ __forceinline__ bf16x8 ld8<float>(const float* p) {
    float4 a = *(const float4*)p, b = *(const float4*)(p + 4);
    bf16x8 r;
    r[0]=(short)f2b(a.x); r[1]=(short)f2b(a.y); r[2]=(short)f2b(a.z); r[3]=(short)f2b(a.w);
    r[4]=(short)f2b(b.x); r[5]=(short)f2b(b.y); r[6]=(short)f2b(b.z); r[7]=(short)f2b(b.w);
    return r;
}

// ---- GEMM tile body (shared by k_gemm and the hybrid prefetch blocks) ----
template<typename XT>
__device__ void gemm_tile(char* ldsbuf,
                          const XT* __restrict__ X, const u16* __restrict__ W,
                          const float* __restrict__ bias, u16* __restrict__ Out,
                          int ldo, int bm, int bn) {
    u16 (*As)[40] = (u16(*)[40])ldsbuf;
    u16 (*Bs)[40] = (u16(*)[40])(ldsbuf + 10240);
    int tid = threadIdx.x;
    int w = tid >> 6, lane = tid & 63;
    int wm = w >> 1, wn = w & 1;
    int l16 = lane & 15, lk = lane >> 4;

    f32x4 acc[4][4];
    #pragma unroll
    for (int i = 0; i < 4; ++i)
        #pragma unroll
        for (int j = 0; j < 4; ++j) acc[i][j] = (f32x4){0.f, 0.f, 0.f, 0.f};

    for (int kt = 0; kt < 32; ++kt) {
        __syncthreads();
        #pragma unroll
        for (int c = 0; c < 2; ++c) {
            int cid = tid + c * 256;
            int rrow = cid >> 2, kc = (cid & 3) * 8;
            *(bf16x8*)(&As[rrow][kc]) = ld8<XT>(X + (long)(bm * 128 + rrow) * HD + kt * 32 + kc);
            *(bf16x8*)(&Bs[rrow][kc]) = ld8<u16>(W + (long)(bn * 128 + rrow) * HD + kt * 32 + kc);
        }
        __syncthreads();
        bf16x8 af[4], bfr[4];
        #pragma unroll
        for (int mt = 0; mt < 4; ++mt)
            af[mt] = *(const bf16x8*)(&As[wm * 64 + mt * 16 + l16][lk * 8]);
        #pragma unroll
        for (int nt = 0; nt < 4; ++nt)
            bfr[nt] = *(const bf16x8*)(&Bs[wn * 64 + nt * 16 + l16][lk * 8]);
        #pragma unroll
        for (int mt = 0; mt < 4; ++mt)
            #pragma unroll
            for (int nt = 0; nt < 4; ++nt)
                acc[mt][nt] = __builtin_amdgcn_mfma_f32_16x16x32_bf16(
                    af[mt], bfr[nt], acc[mt][nt], 0, 0, 0);
    }
    #pragma unroll
    for (int mt = 0; mt < 4; ++mt)
        #pragma unroll
        for (int nt = 0; nt < 4; ++nt) {
            int colg = bn * 128 + wn * 64 + nt * 16 + l16;
            float bv = bias[colg];
            #pragma unroll
            for (int r = 0; r < 4; ++r) {
                int rowg = bm * 128 + wm * 64 + mt * 16 + lk * 4 + r;
                Out[(long)rowg * ldo + colg] = f2b(acc[mt][nt][r] + bv);
            }
        }
}

template<typename XT>
__global__ __launch_bounds__(256) void k_gemm(
    const XT* __restrict__ X, const u16* __restrict__ W,
    const float* __restrict__ bias, u16* __restrict__ Out, int ldo)
{
    __shared__ char ldsbuf[20480];
    gemm_tile<XT>(ldsbuf, X, W, bias, Out, ldo, blockIdx.y, blockIdx.x);
}

// -------- hybrid: blocks [0,64) persist segment s; blocks [64,..) prefetch
// segment s+1's Gx and A on otherwise-idle CUs (no coupling with persist). ----
template<typename XT>
__global__ __launch_bounds__(256, 1) void k_hybrid(
    // persist args (v13)
    const u16* __restrict__ Wmhb, const float* __restrict__ bmh,
    const u16* __restrict__ Wgmb,
    const u16* __restrict__ Ab,    // [SEG][32][1024] segment-local
    const u16* __restrict__ Gxb,   // [SEG][32][4096] segment-local
    u16* eh, u16* em, float* __restrict__ cbuf,
    u16* __restrict__ yb, float* __restrict__ yf,
    float* __restrict__ tail,
    int l, int tbc, int tbi, u32* fM, u32* fH,
    // prefetch args (segment s+1)
    const XT* __restrict__ Xs1, const u16* __restrict__ Wgxb,
    const float* __restrict__ bg, u16* __restrict__ Gx1,
    const u16* __restrict__ Wmxb, const float* __restrict__ bmx,
    u16* __restrict__ A1)
{
    extern __shared__ __align__(16) char lds[];
    const int bid = blockIdx.x;

    if (bid >= 64) {
        // ================= prefetch GEMMs for segment s+1 =================
        int idx = bid - 64;
        if (idx < GXBLK) {
            gemm_tile<XT>(lds, Xs1, Wgxb, bg, Gx1, G4, idx >> 5, idx & 31);
        } else {
            idx -= GXBLK;
            gemm_tile<XT>(lds, Xs1, Wmxb, bmx, A1, HD, idx >> 3, idx & 7);
        }
        return;
    }

    // ===================== persist (byte-identical to v13) =====================
    const int tid = threadIdx.x;
    const int b = bid;
    const int w = tid >> 6, lane = tid & 63;
    const int l16 = lane & 15, lk = lane >> 4;

    for (int it = 0; it < 32; ++it) {
        int cch = tid + it * 256;
        int lr = cch >> 7, k8 = cch & 127;
        int g = lr >> 4, c16 = lr & 15;
        bf16x8 v = *(const bf16x8*)(Wgmb + (long)(g * 1024 + 16 * b + c16) * HD + k8 * 8);
        *(bf16x8*)(lds + SW(lr, lr * 2048 + k8 * 16)) = v;
    }
    for (int it = 0; it < 8; ++it) {
        int cch = tid + it * 256;
        int lr = cch >> 7, k8 = cch & 127;
        bf16x8 v = *(const bf16x8*)(Wmhb + (long)(16 * b + lr) * HD + k8 * 8);
        *(bf16x8*)(lds + 131072 + SW(lr, lr * 2048 + k8 * 16)) = v;
    }
    __syncthreads();

    const int colg = 16 * b + l16;
    const int rt = w & 1;
    const bool isP1 = (w >= 2);

    const float bcol = bmh[colg];
    const char* hbase = (const char*)eh + (size_t)(rt * 16 + l16) * 2048 + lk * 16;
    const char* mbase = (const char*)em + (size_t)(rt * 16 + l16) * 2048 + lk * 16;
    f32x4 creg = (f32x4){0.f, 0.f, 0.f, 0.f};
    if (!isP1)
        #pragma unroll
        for (int r = 0; r < 4; ++r)
            creg[r] = cbuf[(rt * 16 + lk * 4 + r) * HD + colg];

    for (int t = 0; t < SEG; ++t) {
        const u32 gt = (u32)(tbc + t);
        u16 atv[4];
        u16 gxv[4][4];
        if (isP1) {
            const u16* At = Ab + (long)t * NH32;
            #pragma unroll
            for (int r = 0; r < 4; ++r)
                atv[r] = At[(rt * 16 + lk * 4 + r) * HD + colg];
        } else {
            const u16* Gx = Gxb + (long)t * NB * G4;
            #pragma unroll
            for (int g = 0; g < 4; ++g)
                #pragma unroll
                for (int r = 0; r < 4; ++r)
                    gxv[g][r] = Gx[(long)(rt * 16 + lk * 4 + r) * G4 + g * 1024 + colg];
        }
        if (w == 2) pollwait(fH, gt);
        __syncthreads();
        if (isP1) {
            u32x4 hv[32];
            load_row16(hbase, hv);
            f32x4 acc = (f32x4){0.f, 0.f, 0.f, 0.f};
            #pragma unroll
            for (int kt = 0; kt < 32; ++kt) {
                union { u32x4 q; bf16x8 v; } u;
                u.q = hv[kt];
                bf16x8 bfrag = *(const bf16x8*)(lds + 131072 +
                                SW(l16, l16 * 2048 + kt * 64 + lk * 16));
                acc = __builtin_amdgcn_mfma_f32_16x16x32_bf16(u.v, bfrag, acc, 0, 0, 0);
            }
            u16 mu[4];
            #pragma unroll
            for (int r = 0; r < 4; ++r)
                mu[r] = f2b(b2f(atv[r]) * (acc[r] + bcol));
            store_transposed(em, rt * 16, 16 * b, mu);
            asm volatile("s_waitcnt vmcnt(0)" ::: "memory");
            if (lane == 0)
                __hip_atomic_store(fM + b * 32 + rt, gt + 1, ATOMIC_RLX, SCOPE_AGT);
        }
        if (w == 0) pollwait(fM, gt + 1);
        __syncthreads();
        if (!isP1) {
            u32x4 mv[32];
            load_row16(mbase, mv);
            f32x4 gacc[4];
            #pragma unroll
            for (int g = 0; g < 4; ++g) gacc[g] = (f32x4){0.f, 0.f, 0.f, 0.f};
            #pragma unroll
            for (int kt = 0; kt < 32; ++kt) {
                union { u32x4 q; bf16x8 v; } u;
                u.q = mv[kt];
                #pragma unroll
                for (int g = 0; g < 4; ++g) {
                    int lr = g * 16 + l16;
                    bf16x8 bfrag = *(const bf16x8*)(lds + SW(lr, lr * 2048 + kt * 64 + lk * 16));
                    gacc[g] = __builtin_amdgcn_mfma_f32_16x16x32_bf16(u.v, bfrag, gacc[g], 0, 0, 0);
                }
            }
            float hn[4];
            u16 hu[4];
            #pragma unroll
            for (int r = 0; r < 4; ++r) {
                float ig = gacc[0][r] + b2f(gxv[0][r]);
                float fg = gacc[1][r] + b2f(gxv[1][r]);
                float zg = gacc[2][r] + b2f(gxv[2][r]);
                float og = gacc[3][r] + b2f(gxv[3][r]);
                float si = 1.f / (1.f + expf(-ig));
                float sf = 1.f / (1.f + expf(-fg));
                float so = 1.f / (1.f + expf(-og));
                float cn = sf * creg[r] + si * tanhf(zg);
                hn[r] = so * tanhf(cn);
                creg[r] = cn;
                hu[r] = f2b(hn[r]);
            }
            store_transposed(eh, rt * 16, 16 * b, hu);
            asm volatile("s_waitcnt vmcnt(0)" ::: "memory");
            if (lane == 0)
                __hip_atomic_store(fH + b * 32 + rt, gt + 1, ATOMIC_RLX, SCOPE_AGT);
            #pragma unroll
            for (int r = 0; r < 4; ++r) {
                int row = rt * 16 + lk * 4 + r;
                long yidx = (long)(tbi + t) * NH32 + (long)row * HD + colg;
                if (yb) yb[yidx] = f2b(hn[r]); else yf[yidx] = hn[r];
                if (tbi + t == LSEQ - 1) {
                    tail[(long)l * NH32 + row * HD + colg] = hn[r];
                    tail[2L * NH32 + (long)l * NH32 + row * HD + colg] = creg[r];
                }
            }
        }
    }
    if (!isP1)
        #pragma unroll
        for (int r = 0; r < 4; ++r)
            cbuf[(rt * 16 + lk * 4 + r) * HD + colg] = creg[r];
}

extern "C" void kernel_launch(void* const* d_in, const int* in_sizes, int n_in,
                              void* d_out, int out_size, void* d_ws, size_t ws_size,
                              hipStream_t stream) {
    (void)in_sizes; (void)n_in; (void)out_size; (void)ws_size;
    const float* inputs = (const float*)d_in[0];
    const float* Wmx[2] = {(const float*)d_in[1], (const float*)d_in[8]};
    const float* Wmh[2] = {(const float*)d_in[2], (const float*)d_in[9]};
    const float* bmx[2] = {(const float*)d_in[3], (const float*)d_in[10]};
    const float* bmh[2] = {(const float*)d_in[4], (const float*)d_in[11]};
    const float* Wgx[2] = {(const float*)d_in[5], (const float*)d_in[12]};
    const float* Wgm[2] = {(const float*)d_in[6], (const float*)d_in[13]};
    const float* bg[2]  = {(const float*)d_in[7], (const float*)d_in[14]};
    float* out = (float*)d_out;

    char* ws = (char*)d_ws;
    const long MB = 1024L * 1024L;
    u16* Wmxb[2] = {(u16*)(ws + 0 * MB),  (u16*)(ws + 2 * MB)};
    u16* Wmhb[2] = {(u16*)(ws + 4 * MB),  (u16*)(ws + 6 * MB)};
    u16* Wgxb[2] = {(u16*)(ws + 8 * MB),  (u16*)(ws + 16 * MB)};
    u16* Wgmb[2] = {(u16*)(ws + 24 * MB), (u16*)(ws + 32 * MB)};
    u16* Yb    = (u16*)(ws + 40 * MB);   // 32MB layer-0 outputs
    u16* Gxb[2] = {(u16*)(ws + 72 * MB), (u16*)(ws + 88 * MB)};   // 16MB each
    u16* Abf[2] = {(u16*)(ws + 104 * MB), (u16*)(ws + 108 * MB)}; // 4MB each
    char* ex = ws + 112 * MB;
    u16* exch_h = (u16*)ex;                       // 64KB
    u16* exch_m = (u16*)(ex + 65536);             // 64KB
    float* cbuf = (float*)(ex + 131072);          // 128KB
    u32* fM     = (u32*)(ex + 262144);            // 64 x 128B slot lines
    u32* fH     = (u32*)(ex + 262144 + 8192);     // 64 x 128B slot lines

    hipFuncSetAttribute((const void*)&k_hybrid<float>,
                        hipFuncAttributeMaxDynamicSharedMemorySize, PERSIST_LDS);
    hipFuncSetAttribute((const void*)&k_hybrid<u16>,
                        hipFuncAttributeMaxDynamicSharedMemorySize, PERSIST_LDS);

    hipMemsetAsync(ex, 0, 262144 + 16384, stream);

    k_cvt<<<512, 256, 0, stream>>>(Wmx[0], Wmxb[0], (long)HD * HD);
    k_cvt<<<512, 256, 0, stream>>>(Wmx[1], Wmxb[1], (long)HD * HD);
    k_cvt<<<512, 256, 0, stream>>>(Wmh[0], Wmhb[0], (long)HD * HD);
    k_cvt<<<512, 256, 0, stream>>>(Wmh[1], Wmhb[1], (long)HD * HD);
    k_cvt<<<1024, 256, 0, stream>>>(Wgx[0], Wgxb[0], (long)G4 * HD);
    k_cvt<<<1024, 256, 0, stream>>>(Wgx[1], Wgxb[1], (long)G4 * HD);
    k_cvt<<<1024, 256, 0, stream>>>(Wgm[0], Wgmb[0], (long)G4 * HD);
    k_cvt<<<1024, 256, 0, stream>>>(Wgm[1], Wgmb[1], (long)G4 * HD);

    for (int l = 0; l < 2; ++l) {
        // prep segment 0 (standalone; for l=1 needs completed Yb)
        if (l == 0) {
            k_gemm<float><<<dim3(32, 16), 256, 0, stream>>>(inputs, Wgxb[0], bg[0], Gxb[0], G4);
            k_gemm<float><<<dim3(8, 16), 256, 0, stream>>>(inputs, Wmxb[0], bmx[0], Abf[0], HD);
        } else {
            k_gemm<u16><<<dim3(32, 16), 256, 0, stream>>>(Yb, Wgxb[1], bg[1], Gxb[0], G4);
            k_gemm<u16><<<dim3(8, 16), 256, 0, stream>>>(Yb, Wmxb[1], bmx[1], Abf[0], HD);
        }
        for (int s = 0; s < NSEG; ++s) {
            bool pf = (s + 1 < NSEG);
            int grid = pf ? (64 + GXBLK + ABLK) : 64;
            int cur = s & 1, nxt = (s + 1) & 1;
            u16* ybp = l ? nullptr : Yb;
            float* yfp = l ? out : nullptr;
            if (l == 0) {
                const float* xs1 = inputs + (long)(s + 1) * SEG * NB * HD;
                k_hybrid<float><<<grid, 256, PERSIST_LDS, stream>>>(
                    Wmhb[0], bmh[0], Wgmb[0], Abf[cur], Gxb[cur],
                    exch_h, exch_m, cbuf, ybp, yfp, out + YSZ,
                    0, s * SEG, s * SEG, fM, fH,
                    pf ? xs1 : inputs, Wgxb[0], bg[0], Gxb[nxt],
                    Wmxb[0], bmx[0], Abf[nxt]);
            } else {
                const u16* xs1 = Yb + (long)(s + 1) * SEG * NB * HD;
                k_hybrid<u16><<<grid, 256, PERSIST_LDS, stream>>>(
                    Wmhb[1], bmh[1], Wgmb[1], Abf[cur], Gxb[cur],
                    exch_h, exch_m, cbuf, ybp, yfp, out + YSZ,
                    1, LSEQ + s * SEG, s * SEG, fM, fH,
                    pf ? xs1 : Yb, Wgxb[1], bg[1], Gxb[nxt],
                    Wmxb[1], bmx[1], Abf[nxt]);
            }
        }
    }
}

// Round 17
// 14116.306 us; speedup vs baseline: 2.2096x; 1.0012x over previous
//
#include <hip/hip_runtime.h>
#include <hip/hip_bf16.h>

// mLSTM persistent v17: v13 persist (835us/seg, best) + co-resident prefetch.
// Grid capped at 256 blocks (64 persist + 192 grid-striding GEMM blocks) so
// every block is resident from t=0 -> no scheduling queue/outliers.
// L=512, N=32, H=1024, 2 layers. Out: ys | hs(2,32,1024) | cs(2,32,1024), fp32.

typedef unsigned short u16;
typedef unsigned int u32;
typedef unsigned long long u64;
typedef __attribute__((ext_vector_type(8))) short bf16x8;
typedef __attribute__((ext_vector_type(4))) float f32x4;
typedef __attribute__((ext_vector_type(4))) unsigned int u32x4;

#define LSEQ 512
#define NB   32
#define HD   1024
#define G4   4096
#define YSZ  (LSEQ*NB*HD)
#define NH32 (NB*HD)
#define SEG  64
#define NSEG (LSEQ/SEG)
#define PERSIST_LDS 163840   // 128KB Wgm + 32KB Wmh
#define PFBLK 192            // prefetch blocks (grid-stride over 640 tiles)
#define NTILE 640            // 512 Gx tiles + 128 A tiles

#define ATOMIC_RLX __ATOMIC_RELAXED
#define SCOPE_AGT __HIP_MEMORY_SCOPE_AGENT

__device__ __forceinline__ float b2f(u16 u) {
    u32 i = ((u32)u) << 16; float f; __builtin_memcpy(&f, &i, 4); return f;
}
__device__ __forceinline__ u16 f2b(float f) {
    u32 x; __builtin_memcpy(&x, &f, 4);
    return (u16)((x + 0x7fffu + ((x >> 16) & 1u)) >> 16);
}
__device__ __forceinline__ int SW(int row, int byte) { return byte ^ ((row & 7) << 4); }

// v13-proven poll: lane b gathers block b's 8B slot-pair; paced with s_sleep.
__device__ __forceinline__ void pollwait(const u32* flags, u32 target) {
    const int lane = threadIdx.x & 63;
    const u64* p = (const u64*)flags + (size_t)lane * 16;
    for (;;) {
        u64 v = __hip_atomic_load(p, ATOMIC_RLX, SCOPE_AGT);
        u32 lo = (u32)v, hi = (u32)(v >> 32);
        if (__all(lo >= target && hi >= target)) break;
        __builtin_amdgcn_s_sleep(4);
    }
    asm volatile("" ::: "memory");
}

// Consumer: 32x 16B coherence-point loads (sector-coalescing).
__device__ __forceinline__ void load_row16(const char* base, u32x4* dst) {
#pragma unroll
    for (int kt = 0; kt < 32; ++kt) {
        u64 a = (u64)(base + kt * 64);
        asm volatile("global_load_dwordx4 %0, %1, off sc0 sc1"
                     : "=v"(dst[kt]) : "v"(a));
    }
    asm volatile("s_waitcnt vmcnt(0)" ::: "memory");
    __builtin_amdgcn_sched_barrier(0);
}

// Producer: shuffle-transpose; each of lanes 0..63 emits one contiguous u64
// atomic store (row rl, 4 cols). [v13-proven]
__device__ __forceinline__ void store_transposed(u16* ebuf, int rowbase, int colbase,
                                                 const u16 mu[4]) {
    const int lane = threadIdx.x & 63;
    u32 wlo = (u32)mu[0] | ((u32)mu[1] << 16);
    u32 whi = (u32)mu[2] | ((u32)mu[3] << 16);
    const int rl = lane >> 2;
    const int r = rl & 3, lks = rl >> 2;
    u64 outv = 0;
#pragma unroll
    for (int i = 0; i < 4; ++i) {
        int s = lks * 16 + (lane & 3) * 4 + i;
        u32 a  = (u32)__shfl((int)wlo, s);
        u32 bb = (u32)__shfl((int)whi, s);
        u32 pick = (r & 2) ? bb : a;
        u32 val = (r & 1) ? (pick >> 16) : (pick & 0xFFFFu);
        outv |= (u64)val << (16 * i);
    }
    u64* dst = (u64*)(ebuf + (size_t)(rowbase + rl) * HD + colbase + (lane & 3) * 4);
    __hip_atomic_store(dst, outv, ATOMIC_RLX, SCOPE_AGT);
}

// ---------------- f32 -> bf16 conversion ----------------
__global__ void k_cvt(const float* __restrict__ s, u16* __restrict__ d, long n) {
    long i = (long)blockIdx.x * blockDim.x + threadIdx.x;
    long stride = (long)gridDim.x * blockDim.x;
    for (; i < n; i += stride) d[i] = f2b(s[i]);
}

template<typename XT> __device__ __forceinline__ bf16x8 ld8(const XT* p);
template<> __device__ __forceinline__ bf16x8 ld8<u16>(const u16* p) {
    return *(const bf16x8*)p;
}
template<> __device__ __forceinline__ bf16x8 ld8<float>(const float* p) {
    float4 a = *(const float4*)p, b = *(const float4*)(p + 4);
    bf16x8 r;
    r[0]=(short)f2b(a.x); r[1]=(short)f2b(a.y); r[2]=(short)f2b(a.z); r[3]=(short)f2b(a.w);
    r[4]=(short)f2b(b.x); r[5]=(short)f2b(b.y); r[6]=(short)f2b(b.z); r[7]=(short)f2b(b.w);
    return r;
}

// ---- GEMM tile body (shared by k_gemm and the hybrid prefetch blocks) ----
template<typename XT>
__device__ void gemm_tile(char* ldsbuf,
                          const XT* __restrict__ X, const u16* __restrict__ W,
                          const float* __restrict__ bias, u16* __restrict__ Out,
                          int ldo, int bm, int bn) {
    u16 (*As)[40] = (u16(*)[40])ldsbuf;
    u16 (*Bs)[40] = (u16(*)[40])(ldsbuf + 10240);
    int tid = threadIdx.x;
    int w = tid >> 6, lane = tid & 63;
    int wm = w >> 1, wn = w & 1;
    int l16 = lane & 15, lk = lane >> 4;

    f32x4 acc[4][4];
    #pragma unroll
    for (int i = 0; i < 4; ++i)
        #pragma unroll
        for (int j = 0; j < 4; ++j) acc[i][j] = (f32x4){0.f, 0.f, 0.f, 0.f};

    for (int kt = 0; kt < 32; ++kt) {
        __syncthreads();
        #pragma unroll
        for (int c = 0; c < 2; ++c) {
            int cid = tid + c * 256;
            int rrow = cid >> 2, kc = (cid & 3) * 8;
            *(bf16x8*)(&As[rrow][kc]) = ld8<XT>(X + (long)(bm * 128 + rrow) * HD + kt * 32 + kc);
            *(bf16x8*)(&Bs[rrow][kc]) = ld8<u16>(W + (long)(bn * 128 + rrow) * HD + kt * 32 + kc);
        }
        __syncthreads();
        bf16x8 af[4], bfr[4];
        #pragma unroll
        for (int mt = 0; mt < 4; ++mt)
            af[mt] = *(const bf16x8*)(&As[wm * 64 + mt * 16 + l16][lk * 8]);
        #pragma unroll
        for (int nt = 0; nt < 4; ++nt)
            bfr[nt] = *(const bf16x8*)(&Bs[wn * 64 + nt * 16 + l16][lk * 8]);
        #pragma unroll
        for (int mt = 0; mt < 4; ++mt)
            #pragma unroll
            for (int nt = 0; nt < 4; ++nt)
                acc[mt][nt] = __builtin_amdgcn_mfma_f32_16x16x32_bf16(
                    af[mt], bfr[nt], acc[mt][nt], 0, 0, 0);
    }
    #pragma unroll
    for (int mt = 0; mt < 4; ++mt)
        #pragma unroll
        for (int nt = 0; nt < 4; ++nt) {
            int colg = bn * 128 + wn * 64 + nt * 16 + l16;
            float bv = bias[colg];
            #pragma unroll
            for (int r = 0; r < 4; ++r) {
                int rowg = bm * 128 + wm * 64 + mt * 16 + lk * 4 + r;
                Out[(long)rowg * ldo + colg] = f2b(acc[mt][nt][r] + bv);
            }
        }
}

template<typename XT>
__global__ __launch_bounds__(256) void k_gemm(
    const XT* __restrict__ X, const u16* __restrict__ W,
    const float* __restrict__ bias, u16* __restrict__ Out, int ldo)
{
    __shared__ char ldsbuf[20480];
    gemm_tile<XT>(ldsbuf, X, W, bias, Out, ldo, blockIdx.y, blockIdx.x);
}

// -------- hybrid: blocks [0,64) persist segment s (v13-identical); blocks
// [64,256) grid-stride the next segment's 640 prefetch GEMM tiles. --------
template<typename XT>
__global__ __launch_bounds__(256, 1) void k_hybrid(
    const u16* __restrict__ Wmhb, const float* __restrict__ bmh,
    const u16* __restrict__ Wgmb,
    const u16* __restrict__ Ab,    // [SEG][32][1024] segment-local
    const u16* __restrict__ Gxb,   // [SEG][32][4096] segment-local
    u16* eh, u16* em, float* __restrict__ cbuf,
    u16* __restrict__ yb, float* __restrict__ yf,
    float* __restrict__ tail,
    int l, int tbc, int tbi, u32* fM, u32* fH,
    const XT* __restrict__ Xs1, const u16* __restrict__ Wgxb,
    const float* __restrict__ bg, u16* __restrict__ Gx1,
    const u16* __restrict__ Wmxb, const float* __restrict__ bmx,
    u16* __restrict__ A1, int do_pf)
{
    extern __shared__ __align__(16) char lds[];
    const int bid = blockIdx.x;

    if (bid >= 64) {
        if (!do_pf) return;
        // ---- grid-stride prefetch GEMMs for segment s+1 (3-4 tiles each) ----
        for (int idx = bid - 64; idx < NTILE; idx += PFBLK) {
            if (idx < 512)
                gemm_tile<XT>(lds, Xs1, Wgxb, bg, Gx1, G4, idx >> 5, idx & 31);
            else {
                int j = idx - 512;
                gemm_tile<XT>(lds, Xs1, Wmxb, bmx, A1, HD, j >> 3, j & 7);
            }
            __syncthreads();
        }
        return;
    }

    // ===================== persist (byte-identical to v13) =====================
    const int tid = threadIdx.x;
    const int b = bid;
    const int w = tid >> 6, lane = tid & 63;
    const int l16 = lane & 15, lk = lane >> 4;

    for (int it = 0; it < 32; ++it) {
        int cch = tid + it * 256;
        int lr = cch >> 7, k8 = cch & 127;
        int g = lr >> 4, c16 = lr & 15;
        bf16x8 v = *(const bf16x8*)(Wgmb + (long)(g * 1024 + 16 * b + c16) * HD + k8 * 8);
        *(bf16x8*)(lds + SW(lr, lr * 2048 + k8 * 16)) = v;
    }
    for (int it = 0; it < 8; ++it) {
        int cch = tid + it * 256;
        int lr = cch >> 7, k8 = cch & 127;
        bf16x8 v = *(const bf16x8*)(Wmhb + (long)(16 * b + lr) * HD + k8 * 8);
        *(bf16x8*)(lds + 131072 + SW(lr, lr * 2048 + k8 * 16)) = v;
    }
    __syncthreads();

    const int colg = 16 * b + l16;
    const int rt = w & 1;
    const bool isP1 = (w >= 2);

    const float bcol = bmh[colg];
    const char* hbase = (const char*)eh + (size_t)(rt * 16 + l16) * 2048 + lk * 16;
    const char* mbase = (const char*)em + (size_t)(rt * 16 + l16) * 2048 + lk * 16;
    f32x4 creg = (f32x4){0.f, 0.f, 0.f, 0.f};
    if (!isP1)
        #pragma unroll
        for (int r = 0; r < 4; ++r)
            creg[r] = cbuf[(rt * 16 + lk * 4 + r) * HD + colg];

    for (int t = 0; t < SEG; ++t) {
        const u32 gt = (u32)(tbc + t);
        u16 atv[4];
        u16 gxv[4][4];
        if (isP1) {
            const u16* At = Ab + (long)t * NH32;
            #pragma unroll
            for (int r = 0; r < 4; ++r)
                atv[r] = At[(rt * 16 + lk * 4 + r) * HD + colg];
        } else {
            const u16* Gx = Gxb + (long)t * NB * G4;
            #pragma unroll
            for (int g = 0; g < 4; ++g)
                #pragma unroll
                for (int r = 0; r < 4; ++r)
                    gxv[g][r] = Gx[(long)(rt * 16 + lk * 4 + r) * G4 + g * 1024 + colg];
        }
        if (w == 2) pollwait(fH, gt);
        __syncthreads();
        if (isP1) {
            u32x4 hv[32];
            load_row16(hbase, hv);
            f32x4 acc = (f32x4){0.f, 0.f, 0.f, 0.f};
            #pragma unroll
            for (int kt = 0; kt < 32; ++kt) {
                union { u32x4 q; bf16x8 v; } u;
                u.q = hv[kt];
                bf16x8 bfrag = *(const bf16x8*)(lds + 131072 +
                                SW(l16, l16 * 2048 + kt * 64 + lk * 16));
                acc = __builtin_amdgcn_mfma_f32_16x16x32_bf16(u.v, bfrag, acc, 0, 0, 0);
            }
            u16 mu[4];
            #pragma unroll
            for (int r = 0; r < 4; ++r)
                mu[r] = f2b(b2f(atv[r]) * (acc[r] + bcol));
            store_transposed(em, rt * 16, 16 * b, mu);
            asm volatile("s_waitcnt vmcnt(0)" ::: "memory");
            if (lane == 0)
                __hip_atomic_store(fM + b * 32 + rt, gt + 1, ATOMIC_RLX, SCOPE_AGT);
        }
        if (w == 0) pollwait(fM, gt + 1);
        __syncthreads();
        if (!isP1) {
            u32x4 mv[32];
            load_row16(mbase, mv);
            f32x4 gacc[4];
            #pragma unroll
            for (int g = 0; g < 4; ++g) gacc[g] = (f32x4){0.f, 0.f, 0.f, 0.f};
            #pragma unroll
            for (int kt = 0; kt < 32; ++kt) {
                union { u32x4 q; bf16x8 v; } u;
                u.q = mv[kt];
                #pragma unroll
                for (int g = 0; g < 4; ++g) {
                    int lr = g * 16 + l16;
                    bf16x8 bfrag = *(const bf16x8*)(lds + SW(lr, lr * 2048 + kt * 64 + lk * 16));
                    gacc[g] = __builtin_amdgcn_mfma_f32_16x16x32_bf16(u.v, bfrag, gacc[g], 0, 0, 0);
                }
            }
            float hn[4];
            u16 hu[4];
            #pragma unroll
            for (int r = 0; r < 4; ++r) {
                float ig = gacc[0][r] + b2f(gxv[0][r]);
                float fg = gacc[1][r] + b2f(gxv[1][r]);
                float zg = gacc[2][r] + b2f(gxv[2][r]);
                float og = gacc[3][r] + b2f(gxv[3][r]);
                float si = 1.f / (1.f + expf(-ig));
                float sf = 1.f / (1.f + expf(-fg));
                float so = 1.f / (1.f + expf(-og));
                float cn = sf * creg[r] + si * tanhf(zg);
                hn[r] = so * tanhf(cn);
                creg[r] = cn;
                hu[r] = f2b(hn[r]);
            }
            store_transposed(eh, rt * 16, 16 * b, hu);
            asm volatile("s_waitcnt vmcnt(0)" ::: "memory");
            if (lane == 0)
                __hip_atomic_store(fH + b * 32 + rt, gt + 1, ATOMIC_RLX, SCOPE_AGT);
            #pragma unroll
            for (int r = 0; r < 4; ++r) {
                int row = rt * 16 + lk * 4 + r;
                long yidx = (long)(tbi + t) * NH32 + (long)row * HD + colg;
                if (yb) yb[yidx] = f2b(hn[r]); else yf[yidx] = hn[r];
                if (tbi + t == LSEQ - 1) {
                    tail[(long)l * NH32 + row * HD + colg] = hn[r];
                    tail[2L * NH32 + (long)l * NH32 + row * HD + colg] = creg[r];
                }
            }
        }
    }
    if (!isP1)
        #pragma unroll
        for (int r = 0; r < 4; ++r)
            cbuf[(rt * 16 + lk * 4 + r) * HD + colg] = creg[r];
}

extern "C" void kernel_launch(void* const* d_in, const int* in_sizes, int n_in,
                              void* d_out, int out_size, void* d_ws, size_t ws_size,
                              hipStream_t stream) {
    (void)in_sizes; (void)n_in; (void)out_size; (void)ws_size;
    const float* inputs = (const float*)d_in[0];
    const float* Wmx[2] = {(const float*)d_in[1], (const float*)d_in[8]};
    const float* Wmh[2] = {(const float*)d_in[2], (const float*)d_in[9]};
    const float* bmx[2] = {(const float*)d_in[3], (const float*)d_in[10]};
    const float* bmh[2] = {(const float*)d_in[4], (const float*)d_in[11]};
    const float* Wgx[2] = {(const float*)d_in[5], (const float*)d_in[12]};
    const float* Wgm[2] = {(const float*)d_in[6], (const float*)d_in[13]};
    const float* bg[2]  = {(const float*)d_in[7], (const float*)d_in[14]};
    float* out = (float*)d_out;

    char* ws = (char*)d_ws;
    const long MB = 1024L * 1024L;
    u16* Wmxb[2] = {(u16*)(ws + 0 * MB),  (u16*)(ws + 2 * MB)};
    u16* Wmhb[2] = {(u16*)(ws + 4 * MB),  (u16*)(ws + 6 * MB)};
    u16* Wgxb[2] = {(u16*)(ws + 8 * MB),  (u16*)(ws + 16 * MB)};
    u16* Wgmb[2] = {(u16*)(ws + 24 * MB), (u16*)(ws + 32 * MB)};
    u16* Yb    = (u16*)(ws + 40 * MB);   // 32MB layer-0 outputs
    u16* Gxb[2] = {(u16*)(ws + 72 * MB), (u16*)(ws + 88 * MB)};   // 16MB each
    u16* Abf[2] = {(u16*)(ws + 104 * MB), (u16*)(ws + 108 * MB)}; // 4MB each
    char* ex = ws + 112 * MB;
    u16* exch_h = (u16*)ex;                       // 64KB
    u16* exch_m = (u16*)(ex + 65536);             // 64KB
    float* cbuf = (float*)(ex + 131072);          // 128KB
    u32* fM     = (u32*)(ex + 262144);            // 64 x 128B slot lines
    u32* fH     = (u32*)(ex + 262144 + 8192);     // 64 x 128B slot lines

    hipFuncSetAttribute((const void*)&k_hybrid<float>,
                        hipFuncAttributeMaxDynamicSharedMemorySize, PERSIST_LDS);
    hipFuncSetAttribute((const void*)&k_hybrid<u16>,
                        hipFuncAttributeMaxDynamicSharedMemorySize, PERSIST_LDS);

    hipMemsetAsync(ex, 0, 262144 + 16384, stream);

    k_cvt<<<512, 256, 0, stream>>>(Wmx[0], Wmxb[0], (long)HD * HD);
    k_cvt<<<512, 256, 0, stream>>>(Wmx[1], Wmxb[1], (long)HD * HD);
    k_cvt<<<512, 256, 0, stream>>>(Wmh[0], Wmhb[0], (long)HD * HD);
    k_cvt<<<512, 256, 0, stream>>>(Wmh[1], Wmhb[1], (long)HD * HD);
    k_cvt<<<1024, 256, 0, stream>>>(Wgx[0], Wgxb[0], (long)G4 * HD);
    k_cvt<<<1024, 256, 0, stream>>>(Wgx[1], Wgxb[1], (long)G4 * HD);
    k_cvt<<<1024, 256, 0, stream>>>(Wgm[0], Wgmb[0], (long)G4 * HD);
    k_cvt<<<1024, 256, 0, stream>>>(Wgm[1], Wgmb[1], (long)G4 * HD);

    for (int l = 0; l < 2; ++l) {
        // prep segment 0 (standalone; l=1 needs completed Yb)
        if (l == 0) {
            k_gemm<float><<<dim3(32, 16), 256, 0, stream>>>(inputs, Wgxb[0], bg[0], Gxb[0], G4);
            k_gemm<float><<<dim3(8, 16), 256, 0, stream>>>(inputs, Wmxb[0], bmx[0], Abf[0], HD);
        } else {
            k_gemm<u16><<<dim3(32, 16), 256, 0, stream>>>(Yb, Wgxb[1], bg[1], Gxb[0], G4);
            k_gemm<u16><<<dim3(8, 16), 256, 0, stream>>>(Yb, Wmxb[1], bmx[1], Abf[0], HD);
        }
        for (int s = 0; s < NSEG; ++s) {
            int pf = (s + 1 < NSEG) ? 1 : 0;
            int cur = s & 1, nxt = (s + 1) & 1;
            u16* ybp = l ? nullptr : Yb;
            float* yfp = l ? out : nullptr;
            if (l == 0) {
                const float* xs1 = inputs + (long)((s + 1) % NSEG) * SEG * NB * HD;
                k_hybrid<float><<<256, 256, PERSIST_LDS, stream>>>(
                    Wmhb[0], bmh[0], Wgmb[0], Abf[cur], Gxb[cur],
                    exch_h, exch_m, cbuf, ybp, yfp, out + YSZ,
                    0, s * SEG, s * SEG, fM, fH,
                    xs1, Wgxb[0], bg[0], Gxb[nxt],
                    Wmxb[0], bmx[0], Abf[nxt], pf);
            } else {
                const u16* xs1 = Yb + (long)((s + 1) % NSEG) * SEG * NB * HD;
                k_hybrid<u16><<<256, 256, PERSIST_LDS, stream>>>(
                    Wmhb[1], bmh[1], Wgmb[1], Abf[cur], Gxb[cur],
                    exch_h, exch_m, cbuf, ybp, yfp, out + YSZ,
                    1, LSEQ + s * SEG, s * SEG, fM, fH,
                    xs1, Wgxb[1], bg[1], Gxb[nxt],
                    Wmxb[1], bmx[1], Abf[nxt], pf);
            }
        }
    }
}

// Round 18
// 13834.148 us; speedup vs baseline: 2.2546x; 1.0204x over previous
//
#include <hip/hip_runtime.h>
#include <hip/hip_bf16.h>

// mLSTM persistent v13-final (best measured: 13.92ms total, 835us/segment).
// v10 sync skeleton (per-block 128B flag lines, single-poller + barrier
// broadcast, s_sleep pacing) + wide coalesced exchange (16B sc0/sc1 consumer
// loads; shuffle-transposed u64 producer stores).
// L=512, N=32, H=1024, 2 layers. Out: ys | hs(2,32,1024) | cs(2,32,1024), fp32.
//
// Structure: weights (10MB bf16) >> LDS forces 64-block model-parallelism;
// each step algebraically requires 2 all-gathers (m needs all h-cols, g needs
// all m-cols) -> 2 cross-CU sync legs/step x 1024 steps. Each leg ~6.5us of
// serial MALL round-trips (drain-ack, flag-visible, poll-detect, data-read).
// Eight sync designs (counters/flags/tags/parity/sentinels/barrier-free)
// bracket the same ~13us/step floor; this is the sync-latency roofline.

typedef unsigned short u16;
typedef unsigned int u32;
typedef unsigned long long u64;
typedef __attribute__((ext_vector_type(8))) short bf16x8;
typedef __attribute__((ext_vector_type(4))) float f32x4;
typedef __attribute__((ext_vector_type(4))) unsigned int u32x4;

#define LSEQ 512
#define NB   32
#define HD   1024
#define G4   4096
#define YSZ  (LSEQ*NB*HD)
#define NH32 (NB*HD)
#define SEG  64
#define NSEG (LSEQ/SEG)
#define PERSIST_LDS 163840   // 128KB Wgm + 32KB Wmh

#define ATOMIC_RLX __ATOMIC_RELAXED
#define SCOPE_AGT __HIP_MEMORY_SCOPE_AGENT

__device__ __forceinline__ float b2f(u16 u) {
    u32 i = ((u32)u) << 16; float f; __builtin_memcpy(&f, &i, 4); return f;
}
__device__ __forceinline__ u16 f2b(float f) {
    u32 x; __builtin_memcpy(&x, &f, 4);
    return (u16)((x + 0x7fffu + ((x >> 16) & 1u)) >> 16);
}
__device__ __forceinline__ int SW(int row, int byte) { return byte ^ ((row & 7) << 4); }

// Poll: lane b gathers block b's 8B slot-pair (128B line per block); paced.
__device__ __forceinline__ void pollwait(const u32* flags, u32 target) {
    const int lane = threadIdx.x & 63;
    const u64* p = (const u64*)flags + (size_t)lane * 16;
    for (;;) {
        u64 v = __hip_atomic_load(p, ATOMIC_RLX, SCOPE_AGT);
        u32 lo = (u32)v, hi = (u32)(v >> 32);
        if (__all(lo >= target && hi >= target)) break;
        __builtin_amdgcn_s_sleep(4);
    }
    asm volatile("" ::: "memory");
}

// Consumer: 32x 16B coherence-point loads (sector-coalescing, unlike atomics).
__device__ __forceinline__ void load_row16(const char* base, u32x4* dst) {
#pragma unroll
    for (int kt = 0; kt < 32; ++kt) {
        u64 a = (u64)(base + kt * 64);
        asm volatile("global_load_dwordx4 %0, %1, off sc0 sc1"
                     : "=v"(dst[kt]) : "v"(a));
    }
    asm volatile("s_waitcnt vmcnt(0)" ::: "memory");
    __builtin_amdgcn_sched_barrier(0);
}

// Producer: shuffle-transpose so each of 64 lanes emits ONE contiguous u64
// atomic store (row rl, 4 cols) — 8x fewer, 4x wider requests than scattered.
__device__ __forceinline__ void store_transposed(u16* ebuf, int rowbase, int colbase,
                                                 const u16 mu[4]) {
    const int lane = threadIdx.x & 63;
    u32 wlo = (u32)mu[0] | ((u32)mu[1] << 16);
    u32 whi = (u32)mu[2] | ((u32)mu[3] << 16);
    const int rl = lane >> 2;
    const int r = rl & 3, lks = rl >> 2;
    u64 outv = 0;
#pragma unroll
    for (int i = 0; i < 4; ++i) {
        int s = lks * 16 + (lane & 3) * 4 + i;
        u32 a  = (u32)__shfl((int)wlo, s);
        u32 bb = (u32)__shfl((int)whi, s);
        u32 pick = (r & 2) ? bb : a;
        u32 val = (r & 1) ? (pick >> 16) : (pick & 0xFFFFu);
        outv |= (u64)val << (16 * i);
    }
    u64* dst = (u64*)(ebuf + (size_t)(rowbase + rl) * HD + colbase + (lane & 3) * 4);
    __hip_atomic_store(dst, outv, ATOMIC_RLX, SCOPE_AGT);
}

// ---------------- f32 -> bf16 conversion ----------------
__global__ void k_cvt(const float* __restrict__ s, u16* __restrict__ d, long n) {
    long i = (long)blockIdx.x * blockDim.x + threadIdx.x;
    long stride = (long)gridDim.x * blockDim.x;
    for (; i < n; i += stride) d[i] = f2b(s[i]);
}

template<typename XT> __device__ __forceinline__ bf16x8 ld8(const XT* p);
template<> __device__ __forceinline__ bf16x8 ld8<u16>(const u16* p) {
    return *(const bf16x8*)p;
}
template<> __device__ __forceinline__ bf16x8 ld8<float>(const float* p) {
    float4 a = *(const float4*)p, b = *(const float4*)(p + 4);
    bf16x8 r;
    r[0]=(short)f2b(a.x); r[1]=(short)f2b(a.y); r[2]=(short)f2b(a.z); r[3]=(short)f2b(a.w);
    r[4]=(short)f2b(b.x); r[5]=(short)f2b(b.y); r[6]=(short)f2b(b.z); r[7]=(short)f2b(b.w);
    return r;
}

// ------- big GEMM: Out[M][ldo] = bf16(X[M][1024] @ W[ncols][1024]^T + bias) -------
template<typename XT>
__global__ __launch_bounds__(256) void k_gemm(
    const XT* __restrict__ X, const u16* __restrict__ W,
    const float* __restrict__ bias, u16* __restrict__ Out, int ldo)
{
    __shared__ u16 As[128][40];
    __shared__ u16 Bs[128][40];
    int bm = blockIdx.y, bn = blockIdx.x;
    int tid = threadIdx.x;
    int w = tid >> 6, lane = tid & 63;
    int wm = w >> 1, wn = w & 1;
    int l16 = lane & 15, lk = lane >> 4;

    f32x4 acc[4][4];
    #pragma unroll
    for (int i = 0; i < 4; ++i)
        #pragma unroll
        for (int j = 0; j < 4; ++j) acc[i][j] = (f32x4){0.f, 0.f, 0.f, 0.f};

    for (int kt = 0; kt < 32; ++kt) {
        __syncthreads();
        #pragma unroll
        for (int c = 0; c < 2; ++c) {
            int cid = tid + c * 256;
            int rrow = cid >> 2, kc = (cid & 3) * 8;
            *(bf16x8*)(&As[rrow][kc]) = ld8<XT>(X + (long)(bm * 128 + rrow) * HD + kt * 32 + kc);
            *(bf16x8*)(&Bs[rrow][kc]) = ld8<u16>(W + (long)(bn * 128 + rrow) * HD + kt * 32 + kc);
        }
        __syncthreads();
        bf16x8 af[4], bfr[4];
        #pragma unroll
        for (int mt = 0; mt < 4; ++mt)
            af[mt] = *(const bf16x8*)(&As[wm * 64 + mt * 16 + l16][lk * 8]);
        #pragma unroll
        for (int nt = 0; nt < 4; ++nt)
            bfr[nt] = *(const bf16x8*)(&Bs[wn * 64 + nt * 16 + l16][lk * 8]);
        #pragma unroll
        for (int mt = 0; mt < 4; ++mt)
            #pragma unroll
            for (int nt = 0; nt < 4; ++nt)
                acc[mt][nt] = __builtin_amdgcn_mfma_f32_16x16x32_bf16(
                    af[mt], bfr[nt], acc[mt][nt], 0, 0, 0);
    }
    #pragma unroll
    for (int mt = 0; mt < 4; ++mt)
        #pragma unroll
        for (int nt = 0; nt < 4; ++nt) {
            int colg = bn * 128 + wn * 64 + nt * 16 + l16;
            float bv = bias[colg];
            #pragma unroll
            for (int r = 0; r < 4; ++r) {
                int rowg = bm * 128 + wm * 64 + mt * 16 + lk * 4 + r;
                Out[(long)rowg * ldo + colg] = f2b(acc[mt][nt][r] + bv);
            }
        }
}

// ---------------- persistent recurrent kernel (one 64-step segment) ----------------
// 64 blocks x 256 thr, 1 block/CU (160KB LDS). Block b owns h/m-cols [16b,16b+16).
// Uniform loop, 2 barriers/step. Waves 2,3: phase1 (m). Waves 0,1: phase2 (g/h/c).
__global__ __launch_bounds__(256, 1) void k_persist(
    const u16* __restrict__ Wmhb, const float* __restrict__ bmh,
    const u16* __restrict__ Wgmb,
    const u16* __restrict__ Ab,    // [512][32][1024] layer-local (tbi+t indexed)
    const u16* __restrict__ Gxb,   // [SEG][32][4096] segment-local
    u16* eh, u16* em,              // [32][1024] bf16 coherent exchange
    float* __restrict__ cbuf,      // [32][1024] f32 c-state
    u16* __restrict__ yb, float* __restrict__ yf,
    float* __restrict__ tail,      // out + YSZ
    int l, int tbc, int tbi, u32* fM, u32* fH)
{
    extern __shared__ __align__(16) char lds[];
    const int tid = threadIdx.x;
    const int b = blockIdx.x;
    const int w = tid >> 6, lane = tid & 63;
    const int l16 = lane & 15, lk = lane >> 4;

    // ---- stage Wgm slice (4 gates x 16 cols = 128KB) + Wmh slice (16 cols = 32KB) ----
    for (int it = 0; it < 32; ++it) {
        int cch = tid + it * 256;
        int lr = cch >> 7, k8 = cch & 127;
        int g = lr >> 4, c16 = lr & 15;
        bf16x8 v = *(const bf16x8*)(Wgmb + (long)(g * 1024 + 16 * b + c16) * HD + k8 * 8);
        *(bf16x8*)(lds + SW(lr, lr * 2048 + k8 * 16)) = v;
    }
    for (int it = 0; it < 8; ++it) {
        int cch = tid + it * 256;
        int lr = cch >> 7, k8 = cch & 127;
        bf16x8 v = *(const bf16x8*)(Wmhb + (long)(16 * b + lr) * HD + k8 * 8);
        *(bf16x8*)(lds + 131072 + SW(lr, lr * 2048 + k8 * 16)) = v;
    }
    __syncthreads();

    const int colg = 16 * b + l16;
    const int rt = w & 1;                 // row-tile (waves {0,2}->rows 0-15, {1,3}->16-31)
    const bool isP1 = (w >= 2);

    const float bcol = bmh[colg];
    const char* hbase = (const char*)eh + (size_t)(rt * 16 + l16) * 2048 + lk * 16;
    const char* mbase = (const char*)em + (size_t)(rt * 16 + l16) * 2048 + lk * 16;
    f32x4 creg = (f32x4){0.f, 0.f, 0.f, 0.f};
    if (!isP1)
        #pragma unroll
        for (int r = 0; r < 4; ++r)
            creg[r] = cbuf[(rt * 16 + lk * 4 + r) * HD + colg];

    for (int t = 0; t < SEG; ++t) {
        const u32 gt = (u32)(tbc + t);
        // ---- dependency-free prefetches ----
        u16 atv[4];
        u16 gxv[4][4];
        if (isP1) {
            const u16* At = Ab + (long)(tbi + t) * NH32;
            #pragma unroll
            for (int r = 0; r < 4; ++r)
                atv[r] = At[(rt * 16 + lk * 4 + r) * HD + colg];
        } else {
            const u16* Gx = Gxb + (long)t * NB * G4;
            #pragma unroll
            for (int g = 0; g < 4; ++g)
                #pragma unroll
                for (int r = 0; r < 4; ++r)
                    gxv[g][r] = Gx[(long)(rt * 16 + lk * 4 + r) * G4 + g * 1024 + colg];
        }
        // ---- wait: h_{t-1} ready (only wave 2 polls; barrier broadcasts) ----
        if (w == 2) pollwait(fH, gt);
        __syncthreads();
        // ---- phase 1: m = A_t * (h @ Wmh^T + bmh) ----
        if (isP1) {
            u32x4 hv[32];
            load_row16(hbase, hv);
            f32x4 acc = (f32x4){0.f, 0.f, 0.f, 0.f};
            #pragma unroll
            for (int kt = 0; kt < 32; ++kt) {
                union { u32x4 q; bf16x8 v; } u;
                u.q = hv[kt];
                bf16x8 bfrag = *(const bf16x8*)(lds + 131072 +
                                SW(l16, l16 * 2048 + kt * 64 + lk * 16));
                acc = __builtin_amdgcn_mfma_f32_16x16x32_bf16(u.v, bfrag, acc, 0, 0, 0);
            }
            u16 mu[4];
            #pragma unroll
            for (int r = 0; r < 4; ++r)
                mu[r] = f2b(b2f(atv[r]) * (acc[r] + bcol));
            store_transposed(em, rt * 16, 16 * b, mu);
            asm volatile("s_waitcnt vmcnt(0)" ::: "memory");
            if (lane == 0)
                __hip_atomic_store(fM + b * 32 + rt, gt + 1, ATOMIC_RLX, SCOPE_AGT);
        }
        // ---- wait: m_t ready (only wave 0 polls; barrier broadcasts) ----
        if (w == 0) pollwait(fM, gt + 1);
        __syncthreads();
        // ---- phase 2: g = Gx_t + m @ Wgm^T; gates; h,c ----
        if (!isP1) {
            u32x4 mv[32];
            load_row16(mbase, mv);
            f32x4 gacc[4];
            #pragma unroll
            for (int g = 0; g < 4; ++g) gacc[g] = (f32x4){0.f, 0.f, 0.f, 0.f};
            #pragma unroll
            for (int kt = 0; kt < 32; ++kt) {
                union { u32x4 q; bf16x8 v; } u;
                u.q = mv[kt];
                #pragma unroll
                for (int g = 0; g < 4; ++g) {
                    int lr = g * 16 + l16;
                    bf16x8 bfrag = *(const bf16x8*)(lds + SW(lr, lr * 2048 + kt * 64 + lk * 16));
                    gacc[g] = __builtin_amdgcn_mfma_f32_16x16x32_bf16(u.v, bfrag, gacc[g], 0, 0, 0);
                }
            }
            float hn[4];
            u16 hu[4];
            #pragma unroll
            for (int r = 0; r < 4; ++r) {
                float ig = gacc[0][r] + b2f(gxv[0][r]);
                float fg = gacc[1][r] + b2f(gxv[1][r]);
                float zg = gacc[2][r] + b2f(gxv[2][r]);
                float og = gacc[3][r] + b2f(gxv[3][r]);
                float si = 1.f / (1.f + expf(-ig));
                float sf = 1.f / (1.f + expf(-fg));
                float so = 1.f / (1.f + expf(-og));
                float cn = sf * creg[r] + si * tanhf(zg);
                hn[r] = so * tanhf(cn);
                creg[r] = cn;
                hu[r] = f2b(hn[r]);
            }
            store_transposed(eh, rt * 16, 16 * b, hu);
            asm volatile("s_waitcnt vmcnt(0)" ::: "memory");
            if (lane == 0)
                __hip_atomic_store(fH + b * 32 + rt, gt + 1, ATOMIC_RLX, SCOPE_AGT);
            // ---- outputs off the critical path ----
            #pragma unroll
            for (int r = 0; r < 4; ++r) {
                int row = rt * 16 + lk * 4 + r;
                long yidx = (long)(tbi + t) * NH32 + (long)row * HD + colg;
                if (yb) yb[yidx] = f2b(hn[r]); else yf[yidx] = hn[r];
                if (tbi + t == LSEQ - 1) {
                    tail[(long)l * NH32 + row * HD + colg] = hn[r];
                    tail[2L * NH32 + (long)l * NH32 + row * HD + colg] = creg[r];
                }
            }
        }
    }
    if (!isP1)
        #pragma unroll
        for (int r = 0; r < 4; ++r)
            cbuf[(rt * 16 + lk * 4 + r) * HD + colg] = creg[r];
}

extern "C" void kernel_launch(void* const* d_in, const int* in_sizes, int n_in,
                              void* d_out, int out_size, void* d_ws, size_t ws_size,
                              hipStream_t stream) {
    (void)in_sizes; (void)n_in; (void)out_size; (void)ws_size;
    const float* inputs = (const float*)d_in[0];
    const float* Wmx[2] = {(const float*)d_in[1], (const float*)d_in[8]};
    const float* Wmh[2] = {(const float*)d_in[2], (const float*)d_in[9]};
    const float* bmx[2] = {(const float*)d_in[3], (const float*)d_in[10]};
    const float* bmh[2] = {(const float*)d_in[4], (const float*)d_in[11]};
    const float* Wgx[2] = {(const float*)d_in[5], (const float*)d_in[12]};
    const float* Wgm[2] = {(const float*)d_in[6], (const float*)d_in[13]};
    const float* bg[2]  = {(const float*)d_in[7], (const float*)d_in[14]};
    float* out = (float*)d_out;

    char* ws = (char*)d_ws;
    const long MB = 1024L * 1024L;
    u16* Wmxb[2] = {(u16*)(ws + 0 * MB),  (u16*)(ws + 2 * MB)};
    u16* Wmhb[2] = {(u16*)(ws + 4 * MB),  (u16*)(ws + 6 * MB)};
    u16* Wgxb[2] = {(u16*)(ws + 8 * MB),  (u16*)(ws + 16 * MB)};
    u16* Wgmb[2] = {(u16*)(ws + 24 * MB), (u16*)(ws + 32 * MB)};
    u16* Yb  = (u16*)(ws + 40 * MB);   // 32MB bf16 layer-0 outputs
    u16* Ab  = (u16*)(ws + 72 * MB);   // 32MB bf16 A = x@Wmx+bmx (per layer)
    u16* Gxb = (u16*)(ws + 104 * MB);  // 16MB bf16 Gx chunk
    char* ex = ws + 120 * MB;
    u16* exch_h = (u16*)ex;                       // 64KB
    u16* exch_m = (u16*)(ex + 65536);             // 64KB
    float* cbuf = (float*)(ex + 131072);          // 128KB
    u32* fM     = (u32*)(ex + 262144);            // 64 x 128B slot lines
    u32* fH     = (u32*)(ex + 262144 + 8192);     // 64 x 128B slot lines

    hipFuncSetAttribute((const void*)k_persist,
                        hipFuncAttributeMaxDynamicSharedMemorySize, PERSIST_LDS);

    // zero exchange + c + flags each call (graph-replay deterministic)
    hipMemsetAsync(ex, 0, 262144 + 16384, stream);

    k_cvt<<<512, 256, 0, stream>>>(Wmx[0], Wmxb[0], (long)HD * HD);
    k_cvt<<<512, 256, 0, stream>>>(Wmx[1], Wmxb[1], (long)HD * HD);
    k_cvt<<<512, 256, 0, stream>>>(Wmh[0], Wmhb[0], (long)HD * HD);
    k_cvt<<<512, 256, 0, stream>>>(Wmh[1], Wmhb[1], (long)HD * HD);
    k_cvt<<<1024, 256, 0, stream>>>(Wgx[0], Wgxb[0], (long)G4 * HD);
    k_cvt<<<1024, 256, 0, stream>>>(Wgx[1], Wgxb[1], (long)G4 * HD);
    k_cvt<<<1024, 256, 0, stream>>>(Wgm[0], Wgmb[0], (long)G4 * HD);
    k_cvt<<<1024, 256, 0, stream>>>(Wgm[1], Wgmb[1], (long)G4 * HD);

    for (int l = 0; l < 2; ++l) {
        if (l == 0)
            k_gemm<float><<<dim3(8, 128), 256, 0, stream>>>(inputs, Wmxb[0], bmx[0], Ab, HD);
        else
            k_gemm<u16><<<dim3(8, 128), 256, 0, stream>>>(Yb, Wmxb[1], bmx[1], Ab, HD);
        for (int s = 0; s < NSEG; ++s) {
            if (l == 0)
                k_gemm<float><<<dim3(32, 16), 256, 0, stream>>>(
                    inputs + (long)s * SEG * NB * HD, Wgxb[0], bg[0], Gxb, G4);
            else
                k_gemm<u16><<<dim3(32, 16), 256, 0, stream>>>(
                    Yb + (long)s * SEG * NB * HD, Wgxb[1], bg[1], Gxb, G4);
            k_persist<<<64, 256, PERSIST_LDS, stream>>>(
                Wmhb[l], bmh[l], Wgmb[l], Ab, Gxb,
                exch_h, exch_m, cbuf,
                l ? nullptr : Yb, l ? out : nullptr, out + YSZ,
                l, l * LSEQ + s * SEG, s * SEG, fM, fH);
        }
    }
}